// Round 7
// baseline (495.447 us; speedup 1.0000x reference)
//
#include <hip/hip_runtime.h>

#define NN 50000
#define NE 800000
#define HD 128
#define NL 4
#define NC 10
#define NG 256
#define CAP 64            // fixed slots per node; deg ~ Poisson(16), P(deg>64) < 1e-20

typedef __attribute__((ext_vector_type(8))) short short8;    // 8 bf16 = 4 VGPR (MFMA A/B frag)
typedef __attribute__((ext_vector_type(4))) float floatx4;   // MFMA C/D frag

union frg { uint4 u; short8 s; };

__device__ __forceinline__ short8 load_frag(const ushort* p){
  frg f; f.u = *(const uint4*)p; return f.s;
}
__device__ __forceinline__ floatx4 MFMA(short8 a, short8 b, floatx4 c){
  return __builtin_amdgcn_mfma_f32_16x16x32_bf16(a, b, c, 0, 0, 0);
}

__device__ __forceinline__ ushort f2bf(float x){           // RNE fp32->bf16
  unsigned u = __float_as_uint(x);
  return (ushort)((u + 0x7FFFu + ((u >> 16) & 1u)) >> 16);
}
__device__ __forceinline__ float bf2f(ushort b){
  return __uint_as_float(((uint)b) << 16);
}
__device__ __forceinline__ float sigmf(float x){ return 1.0f/(1.0f + __expf(-x)); }
__device__ __forceinline__ float tanhff(float x){ return 2.0f/(1.0f + __expf(-2.0f*x)) - 1.0f; }

// ---------------- prep: convert whh / local_w to bf16; fold biases ----------------
__global__ __launch_bounds__(256) void prep_weights_bf16(
    const float* __restrict__ w_hh, const float* __restrict__ local_w,
    const float* __restrict__ b_ih, const float* __restrict__ b_hh,
    ushort* __restrict__ whh_bf, ushort* __restrict__ lw_bf,
    float* __restrict__ bs)
{
  int idx = blockIdx.x*256 + threadIdx.x;
  if (idx < 49152) whh_bf[idx] = f2bf(w_hh[idx]);
  else if (idx < 65536){ int j = idx - 49152; lw_bf[j] = f2bf(local_w[j]); }
  else if (idx < 66048){
    int j = idx - 65536;       // 0..511: br(128), bz(128), bin(128), bhn(128)
    if (j < 256)      bs[j] = b_ih[j] + b_hh[j];
    else if (j < 384) bs[j] = b_ih[j];          // bin
    else              bs[j] = b_hh[j - 128];    // bhn
  }
}

// ---------------- Veff[l]^T[o][j] = sum_f W[l][j][f] * wih[o][f]  (fp32 acc -> bf16) ----------------
__global__ __launch_bounds__(256) void veff_kernel(
    const float* __restrict__ W, const float* __restrict__ w_ih,
    ushort* __restrict__ veffT)
{
  int idx = blockIdx.x*256 + threadIdx.x;    // l*49152 + o*128 + j
  if (idx >= 4*49152) return;
  int l = idx / 49152, rem = idx % 49152;
  int o = rem >> 7, j = rem & 127;
  const float4* wr = (const float4*)&W[(size_t)(l*128 + j)*128];
  const float4* ir = (const float4*)&w_ih[(size_t)o*128];
  float acc = 0.f;
  #pragma unroll
  for (int q = 0; q < 32; q++){
    float4 a = wr[q], b = ir[q];
    acc += a.x*b.x + a.y*b.y + a.z*b.z + a.w*b.w;
  }
  veffT[idx] = f2bf(acc);
}

__global__ __launch_bounds__(256) void convert_x(const float4* __restrict__ x, ushort4* __restrict__ xbf)
{
  int i = blockIdx.x*256 + threadIdx.x;
  if (i < NN*HD/4){
    float4 v = x[i];
    ushort4 o; o.x=f2bf(v.x); o.y=f2bf(v.y); o.z=f2bf(v.z); o.w=f2bf(v.w);
    xbf[i] = o;
  }
}

// ---------------- CSR build: 8 dst-range slices to kill write amplification ----------------
// (round-2 keeper: sliced build; 48->42us, WRITE 48->29.5MB; near probed scatter floor)
#define NSLICE 8
#define CHUNKS 400
#define EPC (NE/CHUNKS)          // 2000 edges per chunk
__global__ __launch_bounds__(256) void fill_csr_sliced(
    const int* __restrict__ src, const int* __restrict__ dst,
    int* deg, ushort* __restrict__ csrf)
{
  int slice = blockIdx.x & (NSLICE-1);
  int chunk = blockIdx.x >> 3;
  int e0 = chunk * EPC;
  int lo = slice * (NN/NSLICE);
  int hi = lo + (NN/NSLICE);
  for (int e = e0 + threadIdx.x; e < e0 + EPC; e += 256){
    int d = dst[e];
    if (d >= lo && d < hi){
      int s = src[e];
      int pos = atomicAdd(&deg[d], 1);
      if (pos < CAP) csrf[(d << 6) + pos] = (ushort)s;
    }
  }
}

__global__ __launch_bounds__(64) void graph_ptr_kernel(const int* __restrict__ batch, int* __restrict__ gptr)
{
  int g = blockIdx.x*64 + threadIdx.x;
  if (g > NG) return;
  int lo = 0, hi = NN;
  while (lo < hi){
    int mid = (lo + hi) >> 1;
    if (batch[mid] < g) lo = mid + 1; else hi = mid;
  }
  gptr[g] = lo;
}

// ---------------- K2: sumh[n] = sum over fixed-capacity edge list of h[src] ----------------
// 4 nodes per wave (quarter-waves, uint4 = 16 B/lane): one instruction gathers 4 full
// 256B rows = 1KB payload -> half the issue slots; 4-deep batch = 4KB in flight.
// High-occupancy standalone kernel (round-10 lesson: never co-locate with MFMA).
__global__ __launch_bounds__(256) void aggregate_bf16(
    const uint4* __restrict__ m4, const int* __restrict__ deg,
    const ushort* __restrict__ csrf, uint4* __restrict__ aggr4)
{
  int t = threadIdx.x;
  int lane16 = t & 15;
  int nid = blockIdx.x*16 + (t >> 4);      // grid 3125 * 16 = 50000 exactly
  int cnt = deg[nid]; if (cnt > CAP) cnt = CAP;
  const ushort* lst = csrf + (nid << 6);
  float a0=0.f,a1=0.f,a2=0.f,a3=0.f,a4=0.f,a5=0.f,a6=0.f,a7=0.f;
  int j = 0;
  for (; j + 3 < cnt; j += 4){
    int i0 = lst[j], i1 = lst[j+1], i2 = lst[j+2], i3 = lst[j+3];
    uint4 v0 = m4[(size_t)i0*16 + lane16];
    uint4 v1 = m4[(size_t)i1*16 + lane16];
    uint4 v2 = m4[(size_t)i2*16 + lane16];
    uint4 v3 = m4[(size_t)i3*16 + lane16];
    a0 += __uint_as_float(v0.x << 16) + __uint_as_float(v1.x << 16)
        + __uint_as_float(v2.x << 16) + __uint_as_float(v3.x << 16);
    a1 += __uint_as_float(v0.x & 0xFFFF0000u) + __uint_as_float(v1.x & 0xFFFF0000u)
        + __uint_as_float(v2.x & 0xFFFF0000u) + __uint_as_float(v3.x & 0xFFFF0000u);
    a2 += __uint_as_float(v0.y << 16) + __uint_as_float(v1.y << 16)
        + __uint_as_float(v2.y << 16) + __uint_as_float(v3.y << 16);
    a3 += __uint_as_float(v0.y & 0xFFFF0000u) + __uint_as_float(v1.y & 0xFFFF0000u)
        + __uint_as_float(v2.y & 0xFFFF0000u) + __uint_as_float(v3.y & 0xFFFF0000u);
    a4 += __uint_as_float(v0.z << 16) + __uint_as_float(v1.z << 16)
        + __uint_as_float(v2.z << 16) + __uint_as_float(v3.z << 16);
    a5 += __uint_as_float(v0.z & 0xFFFF0000u) + __uint_as_float(v1.z & 0xFFFF0000u)
        + __uint_as_float(v2.z & 0xFFFF0000u) + __uint_as_float(v3.z & 0xFFFF0000u);
    a6 += __uint_as_float(v0.w << 16) + __uint_as_float(v1.w << 16)
        + __uint_as_float(v2.w << 16) + __uint_as_float(v3.w << 16);
    a7 += __uint_as_float(v0.w & 0xFFFF0000u) + __uint_as_float(v1.w & 0xFFFF0000u)
        + __uint_as_float(v2.w & 0xFFFF0000u) + __uint_as_float(v3.w & 0xFFFF0000u);
  }
  for (; j < cnt; j++){
    int s = lst[j];
    uint4 v = m4[(size_t)s*16 + lane16];
    a0 += __uint_as_float(v.x << 16);
    a1 += __uint_as_float(v.x & 0xFFFF0000u);
    a2 += __uint_as_float(v.y << 16);
    a3 += __uint_as_float(v.y & 0xFFFF0000u);
    a4 += __uint_as_float(v.z << 16);
    a5 += __uint_as_float(v.z & 0xFFFF0000u);
    a6 += __uint_as_float(v.w << 16);
    a7 += __uint_as_float(v.w & 0xFFFF0000u);
  }
  uint4 o;
  o.x = (uint)f2bf(a0) | ((uint)f2bf(a1) << 16);
  o.y = (uint)f2bf(a2) | ((uint)f2bf(a3) << 16);
  o.z = (uint)f2bf(a4) | ((uint)f2bf(a5) << 16);
  o.w = (uint)f2bf(a6) | ((uint)f2bf(a7) << 16);
  aggr4[(size_t)nid*16 + lane16] = o;
}

// ---------------- K3: fused GRU via MFMA; round-7: 32 nodes/block ----------------
// Theory: occupancy +50% (R2->R3) bought only -11%, prefetch 0% -> co-resident blocks
// march in phase-lockstep (stage together, load weights together, drain barrier
// together). Halving the block halves every serial phase and roughly doubles resident
// blocks: acc 64->32 AGPR, frags 32->16 VGPR, LDS 49->24.6KB -> ~5 blocks/CU (vs 3),
// grid 1563 (1.2 rounds), more phase diversity. launch_bounds(256,4) caps regs at a
// comfortable 128 (expect ~70 VGPR + 32 AGPR; R4's 64-reg spill cliff avoided).
__global__ __launch_bounds__(256, 4) void gru_mfma4(
    const ushort* __restrict__ sumh_bf, ushort* __restrict__ h_bf_out,
    const ushort* __restrict__ h_bf_in,
    const ushort* __restrict__ veffT, const ushort* __restrict__ whh_bf,
    const float* __restrict__ bs)
{
  __shared__ __align__(16) ushort lds_in[8192];        // 16 KB: 16 chunks of 1 KB
  __shared__ __align__(16) ushort lds_out[32*136];     // 8.5 KB hv bf16, stride 136
  int t = threadIdx.x;
  int wv = t >> 6, lane = t & 63;
  int mrow = lane & 15, quad = lane >> 4;
  int nb = blockIdx.x * 32;

  #pragma unroll
  for (int q = 0; q < 4; q++){
    int c = wv*4 + q;                      // c = arr*8 + tt*4 + kc
    int arr = c >> 3, tt = (c >> 2) & 1, kc = c & 3;
    const ushort* srcb = arr ? h_bf_in : sumh_bf;
    int node = nb + tt*16 + mrow; if (node >= NN) node = NN-1;
    uint4 v = *(const uint4*)&srcb[(size_t)node*HD + kc*32 + quad*8];
    *(uint4*)&lds_in[c*512 + lane*8] = v;
  }
  __syncthreads();

  #pragma unroll
  for (int ftl = 0; ftl < 2; ftl++){
    floatx4 aR[2] = {}, aZ[2] = {}, aIN[2] = {}, aHN[2] = {};
    size_t wbase = (size_t)((wv*2 + ftl)*16 + mrow)*HD + quad*8;

    short8 wih[3], whb[3];
    {
      size_t wo = wbase;                       // kc = 0 ih triple, preloaded
      wih[0] = load_frag(&veffT[wo]);
      wih[1] = load_frag(&veffT[128*HD + wo]);
      wih[2] = load_frag(&veffT[256*HD + wo]);
    }

    #pragma unroll
    for (int kc = 0; kc < 4; kc++){
      short8 fa[2], fh[2];
      #pragma unroll
      for (int tt = 0; tt < 2; tt++){
        fa[tt] = load_frag(&lds_in[((tt<<2) | kc)*512 + lane*8]);
        fh[tt] = load_frag(&lds_in[(8 | (tt<<2) | kc)*512 + lane*8]);
      }
      size_t wo = wbase + kc*32;
      whb[0] = load_frag(&whh_bf[wo]);         // hh triple: consumed after ih MFMAs
      whb[1] = load_frag(&whh_bf[128*HD + wo]);
      whb[2] = load_frag(&whh_bf[256*HD + wo]);
      #pragma unroll
      for (int tt = 0; tt < 2; tt++){
        aR[tt]  = MFMA(fa[tt], wih[0], aR[tt]);
        aZ[tt]  = MFMA(fa[tt], wih[1], aZ[tt]);
        aIN[tt] = MFMA(fa[tt], wih[2], aIN[tt]);
      }
      if (kc < 3){
        size_t wo2 = wbase + (kc+1)*32;        // next ih triple: consumed next iter
        wih[0] = load_frag(&veffT[wo2]);
        wih[1] = load_frag(&veffT[128*HD + wo2]);
        wih[2] = load_frag(&veffT[256*HD + wo2]);
      }
      #pragma unroll
      for (int tt = 0; tt < 2; tt++){
        aR[tt]  = MFMA(fh[tt], whb[0], aR[tt]);
        aZ[tt]  = MFMA(fh[tt], whb[1], aZ[tt]);
        aHN[tt] = MFMA(fh[tt], whb[2], aHN[tt]);
      }
    }

    int feat = wv*32 + ftl*16 + mrow;
    float br  = bs[feat], bz = bs[128+feat], bin = bs[256+feat], bhn = bs[384+feat];
    int kw = ftl*16 + mrow;
    int qq = kw >> 3, jj = kw & 7;
    #pragma unroll
    for (int tt = 0; tt < 2; tt++){
      int cho = (8 | (tt<<2) | wv)*512;          // h chunk, kc = wv
      #pragma unroll
      for (int r = 0; r < 4; r++){
        int nrow = quad*4 + r;
        float rr = sigmf(aR[tt][r] + br);
        float zz = sigmf(aZ[tt][r] + bz);
        float nn = tanhff(aIN[tt][r] + bin + rr*(aHN[tt][r] + bhn));
        float ho = bf2f(lds_in[cho + (qq*16 + nrow)*8 + jj]);
        float hv = (1.f - zz)*nn + zz*ho;
        lds_out[(tt*16 + nrow)*136 + feat] = f2bf(hv);
      }
    }
  }
  __syncthreads();

  #pragma unroll
  for (int p = 0; p < 2; p++){
    int chunk = p*256 + t;
    int node = chunk >> 4, f = (chunk & 15)*8;
    int ng = nb + node;
    if (ng < NN){
      uint4 v = *(const uint4*)&lds_out[node*136 + f];
      *(uint4*)&h_bf_out[(size_t)ng*HD + f] = v;
    }
  }
}

// ---------------- local head: relu(hbf @ local_w^T + b) -> fp32 ----------------
__global__ __launch_bounds__(256) void local_gemm_mfma(
    const ushort* __restrict__ hbf, const ushort* __restrict__ lw_bf,
    const float* __restrict__ bias, float* __restrict__ local)
{
  int wv = threadIdx.x >> 6, lane = threadIdx.x & 63;
  int mt = blockIdx.x*4 + wv;
  if (mt >= NN/16) return;
  int m0 = mt*16, mrow = lane & 15, quad = lane >> 4;
  floatx4 acc[8] = {};
  for (int kc = 0; kc < 4; kc++){
    int k0 = kc*32 + quad*8;
    short8 a = load_frag(&hbf[(size_t)(m0 + mrow)*HD + k0]);
    #pragma unroll
    for (int ft = 0; ft < 8; ft++){
      short8 b = load_frag(&lw_bf[(size_t)(ft*16 + mrow)*HD + k0]);
      acc[ft] = MFMA(a, b, acc[ft]);
    }
  }
  #pragma unroll
  for (int ft = 0; ft < 8; ft++){
    float bv = bias[ft*16 + mrow];
    #pragma unroll
    for (int r = 0; r < 4; r++){
      int n = m0 + quad*4 + r;
      local[(size_t)n*HD + ft*16 + mrow] = fmaxf(acc[ft][r] + bv, 0.f);
    }
  }
}

// ---------------- segmented mean-pool (batch sorted, zero atomics) ----------------
__global__ __launch_bounds__(256) void pool_kernel(
    const float* __restrict__ local, const int* __restrict__ gptr,
    float* __restrict__ pooled)
{
  __shared__ float4 red[8][32];
  int g = blockIdx.x;
  int lane = threadIdx.x & 31;
  int st = threadIdx.x >> 5;
  int s0 = gptr[g], s1 = gptr[g+1];
  float4 acc = make_float4(0,0,0,0);
  for (int n = s0 + st; n < s1; n += 8){
    float4 v = *(const float4*)&local[(size_t)n*HD + lane*4];
    acc.x += v.x; acc.y += v.y; acc.z += v.z; acc.w += v.w;
  }
  red[st][lane] = acc;
  __syncthreads();
  if (st == 0){
    float4 s = red[0][lane];
    #pragma unroll
    for (int i=1;i<8;i++){
      float4 v = red[i][lane];
      s.x += v.x; s.y += v.y; s.z += v.z; s.w += v.w;
    }
    float cnt = (float)(s1 - s0);
    if (cnt < 1.0f) cnt = 1.0f;
    float inv = 1.0f / cnt;
    s.x *= inv; s.y *= inv; s.z *= inv; s.w *= inv;
    *(float4*)&pooled[g*HD + lane*4] = s;
  }
}

// ---------------- classifier + log_softmax ----------------
__global__ __launch_bounds__(64) void classifier_kernel(
    const float* __restrict__ pooled,
    const float* __restrict__ gw, const float* __restrict__ gb,
    float* __restrict__ out)
{
  int g = blockIdx.x;
  int lane = threadIdx.x;
  float p0 = pooled[g*HD + lane];
  float p1 = pooled[g*HD + 64 + lane];
  float vals[NC];
  #pragma unroll
  for (int c=0;c<NC;c++){
    float s = p0*gw[c*HD + lane] + p1*gw[c*HD + 64 + lane];
    #pragma unroll
    for (int off=32; off>0; off>>=1) s += __shfl_down(s, off, 64);
    vals[c] = s;
  }
  if (lane == 0){
    float mx = -1e30f;
    #pragma unroll
    for (int c=0;c<NC;c++){ vals[c] += gb[c]; mx = fmaxf(mx, vals[c]); }
    float se = 0.f;
    #pragma unroll
    for (int c=0;c<NC;c++) se += __expf(vals[c] - mx);
    float lse = mx + __logf(se);
    #pragma unroll
    for (int c=0;c<NC;c++) out[g*NC + c] = vals[c] - lse;
  }
}

extern "C" void kernel_launch(void* const* d_in, const int* in_sizes, int n_in,
                              void* d_out, int out_size, void* d_ws, size_t ws_size,
                              hipStream_t stream)
{
  const float* x        = (const float*)d_in[0];
  const int*   ei       = (const int*)  d_in[1];
  const int*   batch    = (const int*)  d_in[2];
  const float* W        = (const float*)d_in[3];
  const float* w_ih     = (const float*)d_in[4];
  const float* w_hh     = (const float*)d_in[5];
  const float* b_ih     = (const float*)d_in[6];
  const float* b_hh     = (const float*)d_in[7];
  const float* local_w  = (const float*)d_in[8];
  const float* local_b  = (const float*)d_in[9];
  const float* global_w = (const float*)d_in[10];
  const float* global_b = (const float*)d_in[11];
  float* out = (float*)d_out;

  // workspace layout
  char* base = (char*)d_ws;
  ushort* csr_fixed = (ushort*)base;                  // 6.4 MB (NN*64 ushorts)
  char*   R       = base + 25600000;                  // 25.6 MB multi-use region
  ushort* sumh_bf = (ushort*)R;                       //   12.8 MB (live during layers)
  ushort* veffT   = (ushort*)(R + 12800000);          //   384 KB (live during layers)
  ushort* whh_bf  = (ushort*)(R + 13193216);          //   96 KB  (live during layers)
  float*  bsums   = (float*)(R + 13291520);           //   2 KB   (live during layers)
  float*  local   = (float*)R;                        //   25.6 MB (after layers)
  ushort* xbf     = (ushort*)(base + 51200000);       // 12.8 MB
  ushort* hbf     = (ushort*)(base + 64000000);       // 12.8 MB
  ushort* lw_bf   = (ushort*)(base + 76800000);       // 32 KB
  float*  pooled  = (float*)(base + 76832768);        // 128 KB
  int* deg        = (int*)(base + 76963840);          // NN
  int* gptr       = deg + NN;                         // NG+1

  const int* esrc = ei;
  const int* edst = ei + NE;

  hipMemsetAsync(deg, 0, NN*sizeof(int), stream);
  prep_weights_bf16<<<259, 256, 0, stream>>>(w_hh, local_w, b_ih, b_hh, whh_bf, lw_bf, bsums);
  veff_kernel<<<768, 256, 0, stream>>>(W, w_ih, veffT);
  convert_x<<<6250, 256, 0, stream>>>((const float4*)x, (ushort4*)xbf);
  fill_csr_sliced<<<NSLICE*CHUNKS, 256, 0, stream>>>(esrc, edst, deg, csr_fixed);
  graph_ptr_kernel<<<5, 64, 0, stream>>>(batch, gptr);

  // layers: high-occ quarter-wave gather, then 32-node full-feat MFMA GRU
  const ushort* hin_b = xbf;
  for (int l = 0; l < NL; l++){
    aggregate_bf16<<<3125, 256, 0, stream>>>((const uint4*)hin_b, deg, csr_fixed, (uint4*)sumh_bf);
    gru_mfma4<<<1563, 256, 0, stream>>>(sumh_bf, hbf, hin_b,
                                        veffT + (size_t)l*49152, whh_bf, bsums);
    hin_b = hbf;
  }

  local_gemm_mfma<<<782, 256, 0, stream>>>(hbf, lw_bf, local_b, local);
  pool_kernel<<<NG, 256, 0, stream>>>(local, gptr, pooled);
  classifier_kernel<<<NG, 64, 0, stream>>>(pooled, global_w, global_b, out);
}

// Round 8
// 434.988 us; speedup vs baseline: 1.1390x; 1.1390x over previous
//
#include <hip/hip_runtime.h>

#define NN 50000
#define NE 800000
#define HD 128
#define NL 4
#define NC 10
#define NG 256
#define CAP 64            // fixed slots per node; deg ~ Poisson(16), P(deg>64) < 1e-20

typedef __attribute__((ext_vector_type(8))) short short8;    // 8 bf16 = 4 VGPR (MFMA A/B frag)
typedef __attribute__((ext_vector_type(4))) float floatx4;   // MFMA C/D frag

union frg { uint4 u; short8 s; };

__device__ __forceinline__ short8 load_frag(const ushort* p){
  frg f; f.u = *(const uint4*)p; return f.s;
}
__device__ __forceinline__ floatx4 MFMA(short8 a, short8 b, floatx4 c){
  return __builtin_amdgcn_mfma_f32_16x16x32_bf16(a, b, c, 0, 0, 0);
}

__device__ __forceinline__ ushort f2bf(float x){           // RNE fp32->bf16
  unsigned u = __float_as_uint(x);
  return (ushort)((u + 0x7FFFu + ((u >> 16) & 1u)) >> 16);
}
__device__ __forceinline__ float bf2f(ushort b){
  return __uint_as_float(((uint)b) << 16);
}
__device__ __forceinline__ float sigmf(float x){ return 1.0f/(1.0f + __expf(-x)); }
__device__ __forceinline__ float tanhff(float x){ return 2.0f/(1.0f + __expf(-2.0f*x)) - 1.0f; }

// ---------------- prep: convert whh / local_w to bf16; fold biases ----------------
__global__ __launch_bounds__(256) void prep_weights_bf16(
    const float* __restrict__ w_hh, const float* __restrict__ local_w,
    const float* __restrict__ b_ih, const float* __restrict__ b_hh,
    ushort* __restrict__ whh_bf, ushort* __restrict__ lw_bf,
    float* __restrict__ bs)
{
  int idx = blockIdx.x*256 + threadIdx.x;
  if (idx < 49152) whh_bf[idx] = f2bf(w_hh[idx]);
  else if (idx < 65536){ int j = idx - 49152; lw_bf[j] = f2bf(local_w[j]); }
  else if (idx < 66048){
    int j = idx - 65536;       // 0..511: br(128), bz(128), bin(128), bhn(128)
    if (j < 256)      bs[j] = b_ih[j] + b_hh[j];
    else if (j < 384) bs[j] = b_ih[j];          // bin
    else              bs[j] = b_hh[j - 128];    // bhn
  }
}

// ---------------- Veff[l]^T[o][j] = sum_f W[l][j][f] * wih[o][f]  (fp32 acc -> bf16) ----------------
__global__ __launch_bounds__(256) void veff_kernel(
    const float* __restrict__ W, const float* __restrict__ w_ih,
    ushort* __restrict__ veffT)
{
  int idx = blockIdx.x*256 + threadIdx.x;    // l*49152 + o*128 + j
  if (idx >= 4*49152) return;
  int l = idx / 49152, rem = idx % 49152;
  int o = rem >> 7, j = rem & 127;
  const float4* wr = (const float4*)&W[(size_t)(l*128 + j)*128];
  const float4* ir = (const float4*)&w_ih[(size_t)o*128];
  float acc = 0.f;
  #pragma unroll
  for (int q = 0; q < 32; q++){
    float4 a = wr[q], b = ir[q];
    acc += a.x*b.x + a.y*b.y + a.z*b.z + a.w*b.w;
  }
  veffT[idx] = f2bf(acc);
}

__global__ __launch_bounds__(256) void convert_x(const float4* __restrict__ x, ushort4* __restrict__ xbf)
{
  int i = blockIdx.x*256 + threadIdx.x;
  if (i < NN*HD/4){
    float4 v = x[i];
    ushort4 o; o.x=f2bf(v.x); o.y=f2bf(v.y); o.z=f2bf(v.z); o.w=f2bf(v.w);
    xbf[i] = o;
  }
}

// ---------------- CSR build: 8 dst-range slices to kill write amplification ----------------
// (round-2 keeper: sliced build; 48->42us, WRITE 48->29.5MB; near probed scatter floor)
#define NSLICE 8
#define CHUNKS 400
#define EPC (NE/CHUNKS)          // 2000 edges per chunk
__global__ __launch_bounds__(256) void fill_csr_sliced(
    const int* __restrict__ src, const int* __restrict__ dst,
    int* deg, ushort* __restrict__ csrf)
{
  int slice = blockIdx.x & (NSLICE-1);
  int chunk = blockIdx.x >> 3;
  int e0 = chunk * EPC;
  int lo = slice * (NN/NSLICE);
  int hi = lo + (NN/NSLICE);
  for (int e = e0 + threadIdx.x; e < e0 + EPC; e += 256){
    int d = dst[e];
    if (d >= lo && d < hi){
      int s = src[e];
      int pos = atomicAdd(&deg[d], 1);
      if (pos < CAP) csrf[(d << 6) + pos] = (ushort)s;
    }
  }
}

__global__ __launch_bounds__(64) void graph_ptr_kernel(const int* __restrict__ batch, int* __restrict__ gptr)
{
  int g = blockIdx.x*64 + threadIdx.x;
  if (g > NG) return;
  int lo = 0, hi = NN;
  while (lo < hi){
    int mid = (lo + hi) >> 1;
    if (batch[mid] < g) lo = mid + 1; else hi = mid;
  }
  gptr[g] = lo;
}

// ---------------- K2: sumh[n] = sum over fixed-capacity edge list of h[src] ----------------
// 4 nodes per wave (quarter-waves, uint4 = 16 B/lane): one instruction gathers 4 full
// 256B rows = 1KB payload -> half the issue slots; 4-deep batch = 4KB in flight.
// High-occupancy standalone kernel (round-10 lesson: never co-locate with MFMA).
__global__ __launch_bounds__(256) void aggregate_bf16(
    const uint4* __restrict__ m4, const int* __restrict__ deg,
    const ushort* __restrict__ csrf, uint4* __restrict__ aggr4)
{
  int t = threadIdx.x;
  int lane16 = t & 15;
  int nid = blockIdx.x*16 + (t >> 4);      // grid 3125 * 16 = 50000 exactly
  int cnt = deg[nid]; if (cnt > CAP) cnt = CAP;
  const ushort* lst = csrf + (nid << 6);
  float a0=0.f,a1=0.f,a2=0.f,a3=0.f,a4=0.f,a5=0.f,a6=0.f,a7=0.f;
  int j = 0;
  for (; j + 3 < cnt; j += 4){
    int i0 = lst[j], i1 = lst[j+1], i2 = lst[j+2], i3 = lst[j+3];
    uint4 v0 = m4[(size_t)i0*16 + lane16];
    uint4 v1 = m4[(size_t)i1*16 + lane16];
    uint4 v2 = m4[(size_t)i2*16 + lane16];
    uint4 v3 = m4[(size_t)i3*16 + lane16];
    a0 += __uint_as_float(v0.x << 16) + __uint_as_float(v1.x << 16)
        + __uint_as_float(v2.x << 16) + __uint_as_float(v3.x << 16);
    a1 += __uint_as_float(v0.x & 0xFFFF0000u) + __uint_as_float(v1.x & 0xFFFF0000u)
        + __uint_as_float(v2.x & 0xFFFF0000u) + __uint_as_float(v3.x & 0xFFFF0000u);
    a2 += __uint_as_float(v0.y << 16) + __uint_as_float(v1.y << 16)
        + __uint_as_float(v2.y << 16) + __uint_as_float(v3.y << 16);
    a3 += __uint_as_float(v0.y & 0xFFFF0000u) + __uint_as_float(v1.y & 0xFFFF0000u)
        + __uint_as_float(v2.y & 0xFFFF0000u) + __uint_as_float(v3.y & 0xFFFF0000u);
    a4 += __uint_as_float(v0.z << 16) + __uint_as_float(v1.z << 16)
        + __uint_as_float(v2.z << 16) + __uint_as_float(v3.z << 16);
    a5 += __uint_as_float(v0.z & 0xFFFF0000u) + __uint_as_float(v1.z & 0xFFFF0000u)
        + __uint_as_float(v2.z & 0xFFFF0000u) + __uint_as_float(v3.z & 0xFFFF0000u);
    a6 += __uint_as_float(v0.w << 16) + __uint_as_float(v1.w << 16)
        + __uint_as_float(v2.w << 16) + __uint_as_float(v3.w << 16);
    a7 += __uint_as_float(v0.w & 0xFFFF0000u) + __uint_as_float(v1.w & 0xFFFF0000u)
        + __uint_as_float(v2.w & 0xFFFF0000u) + __uint_as_float(v3.w & 0xFFFF0000u);
  }
  for (; j < cnt; j++){
    int s = lst[j];
    uint4 v = m4[(size_t)s*16 + lane16];
    a0 += __uint_as_float(v.x << 16);
    a1 += __uint_as_float(v.x & 0xFFFF0000u);
    a2 += __uint_as_float(v.y << 16);
    a3 += __uint_as_float(v.y & 0xFFFF0000u);
    a4 += __uint_as_float(v.z << 16);
    a5 += __uint_as_float(v.z & 0xFFFF0000u);
    a6 += __uint_as_float(v.w << 16);
    a7 += __uint_as_float(v.w & 0xFFFF0000u);
  }
  uint4 o;
  o.x = (uint)f2bf(a0) | ((uint)f2bf(a1) << 16);
  o.y = (uint)f2bf(a2) | ((uint)f2bf(a3) << 16);
  o.z = (uint)f2bf(a4) | ((uint)f2bf(a5) << 16);
  o.w = (uint)f2bf(a6) | ((uint)f2bf(a7) << 16);
  aggr4[(size_t)nid*16 + lane16] = o;
}

// ---------------- K3: fused GRU via MFMA; 64 nodes/block (R6-exact revert) ----------------
// R7 lesson: 32-node blocks raised occupancy to 29% but halved per-block weight
// amortization (block always reads the full 192KB weight set, each wave its own
// 1/8 row-slice) -> 53us. 64-node + ftl-split + (256,3) = 41us is this structure's
// floor; occupancy/prefetch/granularity levers all exhausted.
__global__ __launch_bounds__(256, 3) void gru_mfma4(
    const ushort* __restrict__ sumh_bf, ushort* __restrict__ h_bf_out,
    const ushort* __restrict__ h_bf_in,
    const ushort* __restrict__ veffT, const ushort* __restrict__ whh_bf,
    const float* __restrict__ bs)
{
  __shared__ __align__(16) ushort lds_in[16384];       // 32 KB: 32 chunks of 1 KB
  __shared__ __align__(16) ushort lds_out[64*136];     // 17 KB hv bf16, stride 136
  int t = threadIdx.x;
  int wv = t >> 6, lane = t & 63;
  int mrow = lane & 15, quad = lane >> 4;
  int nb = blockIdx.x * 64;

  #pragma unroll
  for (int q = 0; q < 8; q++){
    int c = wv*8 + q;                      // c = arr*16 + tt*4 + kc
    int arr = c >> 4, tt = (c >> 2) & 3, kc = c & 3;
    const ushort* srcb = arr ? h_bf_in : sumh_bf;
    int node = nb + tt*16 + mrow; if (node >= NN) node = NN-1;
    uint4 v = *(const uint4*)&srcb[(size_t)node*HD + kc*32 + quad*8];
    *(uint4*)&lds_in[c*512 + lane*8] = v;
  }
  __syncthreads();

  #pragma unroll
  for (int ftl = 0; ftl < 2; ftl++){
    floatx4 aR[4] = {}, aZ[4] = {}, aIN[4] = {}, aHN[4] = {};
    size_t wbase = (size_t)((wv*2 + ftl)*16 + mrow)*HD + quad*8;

    short8 wih[3], whb[3];
    {
      size_t wo = wbase;                       // kc = 0 ih triple, preloaded
      wih[0] = load_frag(&veffT[wo]);
      wih[1] = load_frag(&veffT[128*HD + wo]);
      wih[2] = load_frag(&veffT[256*HD + wo]);
    }

    #pragma unroll
    for (int kc = 0; kc < 4; kc++){
      short8 fa[4], fh[4];
      #pragma unroll
      for (int tt = 0; tt < 4; tt++){
        fa[tt] = load_frag(&lds_in[((tt<<2) | kc)*512 + lane*8]);
        fh[tt] = load_frag(&lds_in[(16 | (tt<<2) | kc)*512 + lane*8]);
      }
      size_t wo = wbase + kc*32;
      whb[0] = load_frag(&whh_bf[wo]);         // hh triple: consumed after ih MFMAs
      whb[1] = load_frag(&whh_bf[128*HD + wo]);
      whb[2] = load_frag(&whh_bf[256*HD + wo]);
      #pragma unroll
      for (int tt = 0; tt < 4; tt++){
        aR[tt]  = MFMA(fa[tt], wih[0], aR[tt]);
        aZ[tt]  = MFMA(fa[tt], wih[1], aZ[tt]);
        aIN[tt] = MFMA(fa[tt], wih[2], aIN[tt]);
      }
      if (kc < 3){
        size_t wo2 = wbase + (kc+1)*32;        // next ih triple: consumed next iter
        wih[0] = load_frag(&veffT[wo2]);
        wih[1] = load_frag(&veffT[128*HD + wo2]);
        wih[2] = load_frag(&veffT[256*HD + wo2]);
      }
      #pragma unroll
      for (int tt = 0; tt < 4; tt++){
        aR[tt]  = MFMA(fh[tt], whb[0], aR[tt]);
        aZ[tt]  = MFMA(fh[tt], whb[1], aZ[tt]);
        aHN[tt] = MFMA(fh[tt], whb[2], aHN[tt]);
      }
    }

    int feat = wv*32 + ftl*16 + mrow;
    float br  = bs[feat], bz = bs[128+feat], bin = bs[256+feat], bhn = bs[384+feat];
    int kw = ftl*16 + mrow;
    int qq = kw >> 3, jj = kw & 7;
    #pragma unroll
    for (int tt = 0; tt < 4; tt++){
      int cho = (16 | (tt<<2) | wv)*512;         // h chunk, kc = wv
      #pragma unroll
      for (int r = 0; r < 4; r++){
        int nrow = quad*4 + r;
        float rr = sigmf(aR[tt][r] + br);
        float zz = sigmf(aZ[tt][r] + bz);
        float nn = tanhff(aIN[tt][r] + bin + rr*(aHN[tt][r] + bhn));
        float ho = bf2f(lds_in[cho + (qq*16 + nrow)*8 + jj]);
        float hv = (1.f - zz)*nn + zz*ho;
        lds_out[(tt*16 + nrow)*136 + feat] = f2bf(hv);
      }
    }
  }
  __syncthreads();

  #pragma unroll
  for (int p = 0; p < 4; p++){
    int chunk = p*256 + t;
    int node = chunk >> 4, f = (chunk & 15)*8;
    int ng = nb + node;
    if (ng < NN){
      uint4 v = *(const uint4*)&lds_out[node*136 + f];
      *(uint4*)&h_bf_out[(size_t)ng*HD + f] = v;
    }
  }
}

// ---------------- fused local head + mean-pool ----------------
// Round-8: relu(hbf @ lw^T + b) computed per 64-node block into LDS (fp32, stride 130
// -> <=2-way bank aliasing), then block-level per-(graph,feat) partial sums with ONE
// atomicAdd each (~190 atomics/block, 150K total to 32K addresses). Eliminates the
// 25.6MB 'local' write + 25.6MB pool re-read + one dispatch. pooled holds SUMS;
// classifier divides by count from gptr.
__global__ __launch_bounds__(256) void local_pool_fused(
    const ushort* __restrict__ hbf, const ushort* __restrict__ lw_bf,
    const float* __restrict__ bias, const int* __restrict__ batch,
    const int* __restrict__ gptr, float* __restrict__ pooled)
{
  __shared__ float lds_loc[64*130];          // 33.3 KB
  int t = threadIdx.x;
  int wv = t >> 6, lane = t & 63;
  int mrow = lane & 15, quad = lane >> 4;
  int mt = blockIdx.x*4 + wv;

  if (mt < NN/16){
    int m0 = mt*16;
    floatx4 acc[8] = {};
    for (int kc = 0; kc < 4; kc++){
      int k0 = kc*32 + quad*8;
      short8 a = load_frag(&hbf[(size_t)(m0 + mrow)*HD + k0]);
      #pragma unroll
      for (int ft = 0; ft < 8; ft++){
        short8 b = load_frag(&lw_bf[(size_t)(ft*16 + mrow)*HD + k0]);
        acc[ft] = MFMA(a, b, acc[ft]);
      }
    }
    #pragma unroll
    for (int ft = 0; ft < 8; ft++){
      float bv = bias[ft*16 + mrow];
      #pragma unroll
      for (int r = 0; r < 4; r++){
        lds_loc[(wv*16 + quad*4 + r)*130 + ft*16 + mrow] = fmaxf(acc[ft][r] + bv, 0.f);
      }
    }
  } else {
    // tail waves (grid 782*4 = 3128 > 3125 tiles): zero their rows, still hit barrier
    #pragma unroll
    for (int rr = 0; rr < 16; rr++){
      int row = wv*16 + rr;
      for (int f = lane; f < 128; f += 64) lds_loc[row*130 + f] = 0.f;
    }
  }
  __syncthreads();

  int nb = blockIdx.x*64;
  int nend = min(nb + 64, NN);
  int feat = t & 127, slot = t >> 7;
  int g0 = batch[nb];
  int g1 = batch[nend - 1];
  for (int g = g0 + slot; g <= g1; g += 2){
    int lo = max(gptr[g], nb), hi = min(gptr[g+1], nend);
    float s = 0.f;
    for (int n = lo; n < hi; n++) s += lds_loc[(n - nb)*130 + feat];
    if (hi > lo) atomicAdd(&pooled[g*HD + feat], s);
  }
}

// ---------------- classifier + log_softmax (pooled = sums; divide by count) ----------------
__global__ __launch_bounds__(64) void classifier_kernel(
    const float* __restrict__ pooled, const int* __restrict__ gptr,
    const float* __restrict__ gw, const float* __restrict__ gb,
    float* __restrict__ out)
{
  int g = blockIdx.x;
  int lane = threadIdx.x;
  int cnt = gptr[g+1] - gptr[g];
  float inv = 1.0f / (float)(cnt > 0 ? cnt : 1);
  float p0 = pooled[g*HD + lane] * inv;
  float p1 = pooled[g*HD + 64 + lane] * inv;
  float vals[NC];
  #pragma unroll
  for (int c=0;c<NC;c++){
    float s = p0*gw[c*HD + lane] + p1*gw[c*HD + 64 + lane];
    #pragma unroll
    for (int off=32; off>0; off>>=1) s += __shfl_down(s, off, 64);
    vals[c] = s;
  }
  if (lane == 0){
    float mx = -1e30f;
    #pragma unroll
    for (int c=0;c<NC;c++){ vals[c] += gb[c]; mx = fmaxf(mx, vals[c]); }
    float se = 0.f;
    #pragma unroll
    for (int c=0;c<NC;c++) se += __expf(vals[c] - mx);
    float lse = mx + __logf(se);
    #pragma unroll
    for (int c=0;c<NC;c++) out[g*NC + c] = vals[c] - lse;
  }
}

extern "C" void kernel_launch(void* const* d_in, const int* in_sizes, int n_in,
                              void* d_out, int out_size, void* d_ws, size_t ws_size,
                              hipStream_t stream)
{
  const float* x        = (const float*)d_in[0];
  const int*   ei       = (const int*)  d_in[1];
  const int*   batch    = (const int*)  d_in[2];
  const float* W        = (const float*)d_in[3];
  const float* w_ih     = (const float*)d_in[4];
  const float* w_hh     = (const float*)d_in[5];
  const float* b_ih     = (const float*)d_in[6];
  const float* b_hh     = (const float*)d_in[7];
  const float* local_w  = (const float*)d_in[8];
  const float* local_b  = (const float*)d_in[9];
  const float* global_w = (const float*)d_in[10];
  const float* global_b = (const float*)d_in[11];
  float* out = (float*)d_out;

  // workspace layout
  char* base = (char*)d_ws;
  ushort* csr_fixed = (ushort*)base;                  // 6.4 MB (NN*64 ushorts)
  char*   R       = base + 25600000;                  // 25.6 MB multi-use region
  ushort* sumh_bf = (ushort*)R;                       //   12.8 MB (live during layers)
  ushort* veffT   = (ushort*)(R + 12800000);          //   384 KB (live during layers)
  ushort* whh_bf  = (ushort*)(R + 13193216);          //   96 KB  (live during layers)
  float*  bsums   = (float*)(R + 13291520);           //   2 KB   (live during layers)
  ushort* xbf     = (ushort*)(base + 51200000);       // 12.8 MB
  ushort* hbf     = (ushort*)(base + 64000000);       // 12.8 MB
  ushort* lw_bf   = (ushort*)(base + 76800000);       // 32 KB
  float*  pooled  = (float*)(base + 76832768);        // 128 KB
  int* deg        = (int*)(base + 76963840);          // NN
  int* gptr       = deg + NN;                         // NG+1

  const int* esrc = ei;
  const int* edst = ei + NE;

  hipMemsetAsync(deg, 0, NN*sizeof(int), stream);
  hipMemsetAsync(pooled, 0, NG*HD*sizeof(float), stream);
  prep_weights_bf16<<<259, 256, 0, stream>>>(w_hh, local_w, b_ih, b_hh, whh_bf, lw_bf, bsums);
  veff_kernel<<<768, 256, 0, stream>>>(W, w_ih, veffT);
  convert_x<<<6250, 256, 0, stream>>>((const float4*)x, (ushort4*)xbf);
  fill_csr_sliced<<<NSLICE*CHUNKS, 256, 0, stream>>>(esrc, edst, deg, csr_fixed);
  graph_ptr_kernel<<<5, 64, 0, stream>>>(batch, gptr);

  // layers: high-occ quarter-wave gather, then 64-node full-feat MFMA GRU
  const ushort* hin_b = xbf;
  for (int l = 0; l < NL; l++){
    aggregate_bf16<<<3125, 256, 0, stream>>>((const uint4*)hin_b, deg, csr_fixed, (uint4*)sumh_bf);
    gru_mfma4<<<782, 256, 0, stream>>>(sumh_bf, hbf, hin_b,
                                       veffT + (size_t)l*49152, whh_bf, bsums);
    hin_b = hbf;
  }

  local_pool_fused<<<782, 256, 0, stream>>>(hbf, lw_bf, local_b, batch, gptr, pooled);
  classifier_kernel<<<NG, 64, 0, stream>>>(pooled, gptr, global_w, global_b, out);
}